// Round 1
// 273.261 us; speedup vs baseline: 1.1138x; 1.1138x over previous
//
#include <hip/hip_runtime.h>
#include <hip/hip_fp16.h>

#define N_NODES 50000
#define N_EDGES 600000
#define NBLK 49  // ceil(50000/1024)

typedef unsigned int u32;
typedef _Float16 v8h __attribute__((ext_vector_type(8)));
typedef _Float16 v4h __attribute__((ext_vector_type(4)));
typedef float v4f __attribute__((ext_vector_type(4)));

__device__ __forceinline__ float2 h2f2(u32 u) {
    __half2 h = *(__half2*)&u;
    return __half22float2(h);
}

// ---------------- adj layout detection (int64 vs int32), computed per-wave ----------------
__device__ __forceinline__ int calc_mode(const int* __restrict__ adj_w) {
    // int64 iff the high words of the first 64 entries are all zero
    int l = threadIdx.x & 63;
    unsigned long long b = __ballot(adj_w[2 * l + 1] != 0);
    return (b == 0ull) ? 1 : 0;
}
__device__ __forceinline__ int adj_to(const int* a, int m, int e) {
    return m ? a[4 * e + 2] : a[2 * e + 1];
}
__device__ __forceinline__ int adj_fro(const int* a, int m, int e) {
    return m ? a[4 * e] : a[2 * e];
}

#define COUNT_B 2344   // ceil(600000/256)
#define WPREP_B 344    // ceil(88064/256)
#define IN_B    1563   // ceil(50000/32)

// ---- merged: edge count (CSR degree) + weight transpose/convert ----
__global__ void k_count_prep(const int* __restrict__ adj_w, int* __restrict__ deg,
                             const float* __restrict__ W_in,
                             const float* __restrict__ W_comb,
                             const float* __restrict__ W_out,
                             _Float16* __restrict__ WinT,
                             _Float16* __restrict__ WcombT,
                             _Float16* __restrict__ WoutT) {
    if (blockIdx.x < COUNT_B) {
        int m = calc_mode(adj_w);
        int e = blockIdx.x * 256 + threadIdx.x;
        if (e < N_EDGES) atomicAdd(&deg[adj_to(adj_w, m, e)], 1);
        return;
    }
    int idx = (blockIdx.x - COUNT_B) * 256 + threadIdx.x;
    if (idx < 16384) {
        int n = idx & 127, k = idx >> 7;
        WinT[n * 128 + k] = (_Float16)W_in[k * 128 + n];
    } else if (idx < 16384 + 65536) {
        int j = idx - 16384;
        int l = j >> 15, r = j & 32767;
        int n = r & 127, k = r >> 7;
        WcombT[l * 32768 + n * 256 + k] = (_Float16)W_comb[l * 32768 + k * 128 + n];
    } else if (idx < 16384 + 65536 + 6144) {
        int j = idx - 81920;
        int n = j >> 7, k = j & 127;
        WoutT[n * 128 + k] = (n < 40) ? (_Float16)W_out[k * 40 + n] : (_Float16)0.f;
    }
}

// ---------------- CSR scan ----------------
__global__ void k_scan1(const int* __restrict__ deg, int* __restrict__ row_ptr,
                        int* __restrict__ bsum) {
    __shared__ int s[1024];
    int tid = threadIdx.x, i = blockIdx.x * 1024 + tid;
    int v = (i < N_NODES) ? deg[i] : 0;
    s[tid] = v;
    __syncthreads();
    for (int off = 1; off < 1024; off <<= 1) {
        int t = (tid >= off) ? s[tid - off] : 0;
        __syncthreads();
        s[tid] += t;
        __syncthreads();
    }
    if (i < N_NODES) row_ptr[i] = s[tid] - v;
    if (tid == 1023) bsum[blockIdx.x] = s[1023];
}

// ---- merged scan2+scan3: each block reduces its own block-prefix of bsum ----
__global__ void k_scan23(const int* __restrict__ deg, int* __restrict__ row_ptr,
                         const int* __restrict__ bsum, int* __restrict__ cursor,
                         float* __restrict__ inv_deg) {
    __shared__ int sbase;
    int tid = threadIdx.x;
    if (tid < 64) {
        int v = (tid < NBLK && tid < (int)blockIdx.x) ? bsum[tid] : 0;
#pragma unroll
        for (int off = 32; off > 0; off >>= 1) v += __shfl_down(v, off);
        if (tid == 0) sbase = v;
    }
    __syncthreads();
    int i = blockIdx.x * 1024 + tid;
    if (i < N_NODES) {
        int rp = row_ptr[i] + sbase;
        row_ptr[i] = rp;
        cursor[i] = rp;
        inv_deg[i] = 1.0f / fmaxf((float)deg[i], 1.0f);
    }
    if (i == 0) row_ptr[N_NODES] = N_EDGES;
}

// ---- merged: CSR fill (atomic scatter) + input GEMM h = relu(X @ W_in + b) ----
// blocks [0,COUNT_B): fill; blocks [COUNT_B, COUNT_B+IN_B): MFMA M-tile 32, K=128, N=128
__global__ __launch_bounds__(256, 2) void k_fill_in(const int* __restrict__ adj_w,
                                                    int* __restrict__ cursor,
                                                    int* __restrict__ edge_src,
                                                    const float* __restrict__ X,
                                                    const _Float16* __restrict__ WT,
                                                    const float* __restrict__ bias,
                                                    _Float16* __restrict__ h) {
    __shared__ __align__(16) _Float16 xs[32][136];
    if (blockIdx.x < COUNT_B) {
        int m = calc_mode(adj_w);
        int e = blockIdx.x * 256 + threadIdx.x;
        if (e < N_EDGES) {
            int to = adj_to(adj_w, m, e);
            int slot = atomicAdd(&cursor[to], 1);
            edge_src[slot] = adj_fro(adj_w, m, e);
        }
        return;
    }
    const int t0 = threadIdx.x, w = t0 >> 6, l = t0 & 63;
    const int R0 = (blockIdx.x - COUNT_B) * 32;
    const float4* X4 = (const float4*)X;
#pragma unroll
    for (int i = 0; i < 4; i++) {
        int idx = i * 256 + t0;
        int row = idx >> 5, c4 = idx & 31;
        int rr = R0 + row;
        if (rr > N_NODES - 1) rr = N_NODES - 1;
        float4 v = X4[(size_t)rr * 32 + c4];
        v4h hv = {(_Float16)v.x, (_Float16)v.y, (_Float16)v.z, (_Float16)v.w};
        *(v4h*)&xs[row][c4 * 4] = hv;
    }
    const int ch = w & 1, rh = w >> 1;
    v8h wf[4][4];
#pragma unroll
    for (int t = 0; t < 4; t++)
#pragma unroll
        for (int s = 0; s < 4; s++) {
            int n = ch * 64 + t * 16 + (l & 15);
            int k = s * 32 + (l >> 4) * 8;
            wf[t][s] = *(const v8h*)&WT[n * 128 + k];
        }
    v4f acc[4];
#pragma unroll
    for (int t = 0; t < 4; t++) acc[t] = (v4f){0.f, 0.f, 0.f, 0.f};
    __syncthreads();
#pragma unroll
    for (int s = 0; s < 4; s++) {
        v8h a = *(const v8h*)&xs[rh * 16 + (l & 15)][s * 32 + (l >> 4) * 8];
#pragma unroll
        for (int t = 0; t < 4; t++)
            acc[t] = __builtin_amdgcn_mfma_f32_16x16x32_f16(a, wf[t][s], acc[t], 0, 0, 0);
    }
#pragma unroll
    for (int t = 0; t < 4; t++) {
        int col = ch * 64 + t * 16 + (l & 15);
        float b = bias[col];
#pragma unroll
        for (int i = 0; i < 4; i++) {
            int row = R0 + rh * 16 + (l >> 4) * 4 + i;
            if (row < N_NODES)
                h[(size_t)row * 128 + col] = (_Float16)fmaxf(acc[t][i] + b, 0.f);
        }
    }
}

// ---- gather v2: dual-edge 8B loads. lanes 0-31 = even edge, 32-63 = odd edge ----
__global__ __launch_bounds__(256) void k_gather(const uint2* __restrict__ h4,
                                                uint2* __restrict__ msg4,
                                                const int* __restrict__ row_ptr,
                                                const int* __restrict__ edge_src,
                                                const float* __restrict__ inv_deg) {
    const int w = threadIdx.x >> 6, l = threadIdx.x & 63;
    const int half = l >> 5, c = l & 31;  // c: which 8B chunk of the 256B row
    const int wid = blockIdx.x * 4 + w, nw = gridDim.x * 4;
    for (int row = wid; row < N_NODES; row += nw) {
        const int e0 = row_ptr[row], e1 = row_ptr[row + 1];
        float a0 = 0.f, a1 = 0.f, a2 = 0.f, a3 = 0.f;
        for (int bse = e0; bse < e1; bse += 8) {
            uint2 v[4];
#pragma unroll
            for (int i = 0; i < 4; i++) {
                int ee = bse + 2 * i + half;
                int idx = (ee < e1) ? ee : (e1 - 1);
                v[i] = h4[(size_t)edge_src[idx] * 32 + c];
            }
#pragma unroll
            for (int i = 0; i < 4; i++) {
                if (bse + 2 * i + half < e1) {
                    float2 f0 = h2f2(v[i].x), f1 = h2f2(v[i].y);
                    a0 += f0.x;
                    a1 += f0.y;
                    a2 += f1.x;
                    a3 += f1.y;
                }
            }
        }
        a0 += __shfl_xor(a0, 32);
        a1 += __shfl_xor(a1, 32);
        a2 += __shfl_xor(a2, 32);
        a3 += __shfl_xor(a3, 32);
        if (half == 0) {
            const float inv = inv_deg[row];
            __half2 o0 = __floats2half2_rn(a0 * inv, a1 * inv);
            __half2 o1 = __floats2half2_rn(a2 * inv, a3 * inv);
            uint2 o;
            o.x = *(u32*)&o0;
            o.y = *(u32*)&o1;
            msg4[(size_t)row * 32 + c] = o;
        }
    }
}

// ---- MFMA layer GEMM: hout = relu([h|msg] @ Wc + b); M-tile 64, K=256, N=128 ----
__global__ __launch_bounds__(256, 2) void k_layer(const _Float16* __restrict__ hin,
                                                  const _Float16* __restrict__ msg,
                                                  const _Float16* __restrict__ WT,
                                                  const float* __restrict__ bias,
                                                  _Float16* __restrict__ hout) {
    __shared__ __align__(16) _Float16 xs[64][264];  // 33.8KB
    const int t0 = threadIdx.x, w = t0 >> 6, l = t0 & 63;
    const int R0 = blockIdx.x * 64;
    const uint4* h4 = (const uint4*)hin;
    const uint4* m4 = (const uint4*)msg;
#pragma unroll
    for (int i = 0; i < 8; i++) {
        int idx = i * 256 + t0;
        int row = idx >> 5, c16 = idx & 31;
        int rr = R0 + row;
        if (rr > N_NODES - 1) rr = N_NODES - 1;
        uint4 v = (c16 < 16) ? h4[(size_t)rr * 16 + c16] : m4[(size_t)rr * 16 + (c16 - 16)];
        *(uint4*)&xs[row][c16 * 8] = v;
    }
    const int ch = w & 1, rh = w >> 1;
    v8h wf[4][8];
#pragma unroll
    for (int t = 0; t < 4; t++)
#pragma unroll
        for (int s = 0; s < 8; s++) {
            int n = ch * 64 + t * 16 + (l & 15);
            int k = s * 32 + (l >> 4) * 8;
            wf[t][s] = *(const v8h*)&WT[n * 256 + k];
        }
    v4f acc[2][4];
#pragma unroll
    for (int sub = 0; sub < 2; sub++)
#pragma unroll
        for (int t = 0; t < 4; t++) acc[sub][t] = (v4f){0.f, 0.f, 0.f, 0.f};
    __syncthreads();
#pragma unroll
    for (int s = 0; s < 8; s++) {
#pragma unroll
        for (int sub = 0; sub < 2; sub++) {
            v8h a = *(const v8h*)&xs[rh * 32 + sub * 16 + (l & 15)][s * 32 + (l >> 4) * 8];
#pragma unroll
            for (int t = 0; t < 4; t++)
                acc[sub][t] = __builtin_amdgcn_mfma_f32_16x16x32_f16(a, wf[t][s], acc[sub][t], 0, 0, 0);
        }
    }
#pragma unroll
    for (int sub = 0; sub < 2; sub++)
#pragma unroll
        for (int t = 0; t < 4; t++) {
            int col = ch * 64 + t * 16 + (l & 15);
            float b = bias[col];
#pragma unroll
            for (int i = 0; i < 4; i++) {
                int row = R0 + rh * 32 + sub * 16 + (l >> 4) * 4 + i;
                if (row < N_NODES)
                    hout[(size_t)row * 128 + col] = (_Float16)fmaxf(acc[sub][t][i] + b, 0.f);
            }
        }
}

// ---- fused layer-2 + out: h2 = relu([h|msg] @ Wc + b) staged in LDS, then
// out = h2 @ W_out + b_out directly. Saves the 25.6MB hA round-trip. ----
__global__ __launch_bounds__(256, 2) void k_layer_out(const _Float16* __restrict__ hin,
                                                      const _Float16* __restrict__ msg,
                                                      const _Float16* __restrict__ WT,
                                                      const float* __restrict__ bias,
                                                      const _Float16* __restrict__ WoT,
                                                      const float* __restrict__ bias_o,
                                                      float* __restrict__ outp) {
    __shared__ __align__(16) _Float16 xs[64][264];
    const int t0 = threadIdx.x, w = t0 >> 6, l = t0 & 63;
    const int R0 = blockIdx.x * 64;
    const uint4* h4 = (const uint4*)hin;
    const uint4* m4 = (const uint4*)msg;
#pragma unroll
    for (int i = 0; i < 8; i++) {
        int idx = i * 256 + t0;
        int row = idx >> 5, c16 = idx & 31;
        int rr = R0 + row;
        if (rr > N_NODES - 1) rr = N_NODES - 1;
        uint4 v = (c16 < 16) ? h4[(size_t)rr * 16 + c16] : m4[(size_t)rr * 16 + (c16 - 16)];
        *(uint4*)&xs[row][c16 * 8] = v;
    }
    const int ch = w & 1, rh = w >> 1;
    v8h wf[4][8];
#pragma unroll
    for (int t = 0; t < 4; t++)
#pragma unroll
        for (int s = 0; s < 8; s++) {
            int n = ch * 64 + t * 16 + (l & 15);
            int k = s * 32 + (l >> 4) * 8;
            wf[t][s] = *(const v8h*)&WT[n * 256 + k];
        }
    v4f acc[2][4];
#pragma unroll
    for (int sub = 0; sub < 2; sub++)
#pragma unroll
        for (int t = 0; t < 4; t++) acc[sub][t] = (v4f){0.f, 0.f, 0.f, 0.f};
    __syncthreads();
#pragma unroll
    for (int s = 0; s < 8; s++) {
#pragma unroll
        for (int sub = 0; sub < 2; sub++) {
            v8h a = *(const v8h*)&xs[rh * 32 + sub * 16 + (l & 15)][s * 32 + (l >> 4) * 8];
#pragma unroll
            for (int t = 0; t < 4; t++)
                acc[sub][t] = __builtin_amdgcn_mfma_f32_16x16x32_f16(a, wf[t][s], acc[sub][t], 0, 0, 0);
        }
    }
    __syncthreads();  // all xs reads done; safe to overwrite with h2 tile
    _Float16* hs = &xs[0][0];  // reused as [64][136]
#pragma unroll
    for (int sub = 0; sub < 2; sub++)
#pragma unroll
        for (int t = 0; t < 4; t++) {
            int col = ch * 64 + t * 16 + (l & 15);
            float b = bias[col];
#pragma unroll
            for (int i = 0; i < 4; i++) {
                int lrow = rh * 32 + sub * 16 + (l >> 4) * 4 + i;
                hs[lrow * 136 + col] = (_Float16)fmaxf(acc[sub][t][i] + b, 0.f);
            }
        }
    v8h wo[3][4];
#pragma unroll
    for (int t = 0; t < 3; t++)
#pragma unroll
        for (int s = 0; s < 4; s++) {
            int n = t * 16 + (l & 15);
            int k = s * 32 + (l >> 4) * 8;
            wo[t][s] = *(const v8h*)&WoT[n * 128 + k];
        }
    v4f acc2[3];
#pragma unroll
    for (int t = 0; t < 3; t++) acc2[t] = (v4f){0.f, 0.f, 0.f, 0.f};
    __syncthreads();
#pragma unroll
    for (int s = 0; s < 4; s++) {
        v8h a = *(const v8h*)&hs[(w * 16 + (l & 15)) * 136 + s * 32 + (l >> 4) * 8];
#pragma unroll
        for (int t = 0; t < 3; t++)
            acc2[t] = __builtin_amdgcn_mfma_f32_16x16x32_f16(a, wo[t][s], acc2[t], 0, 0, 0);
    }
#pragma unroll
    for (int t = 0; t < 3; t++) {
        int col = t * 16 + (l & 15);
        if (col < 40) {
            float b = bias_o[col];
#pragma unroll
            for (int i = 0; i < 4; i++) {
                int row = R0 + w * 16 + (l >> 4) * 4 + i;
                if (row < N_NODES) outp[(size_t)row * 40 + col] = acc2[t][i] + b;
            }
        }
    }
}

extern "C" void kernel_launch(void* const* d_in, const int* in_sizes, int n_in,
                              void* d_out, int out_size, void* d_ws, size_t ws_size,
                              hipStream_t stream) {
    int ix[8] = {0, 1, 2, 3, 4, 5, 6, 7};
    int tmp[8] = {-1, -1, -1, -1, -1, -1, -1, -1};
    for (int i = 0; i < n_in && i < 8; i++) {
        switch (in_sizes[i]) {
            case 6400000: tmp[0] = i; break;
            case 1200000: case 2400000: tmp[1] = i; break;
            case 16384:   tmp[2] = i; break;
            case 128:     tmp[3] = i; break;
            case 65536:   tmp[4] = i; break;
            case 256:     tmp[5] = i; break;
            case 5120:    tmp[6] = i; break;
            case 40:      tmp[7] = i; break;
        }
    }
    int found = 0;
    for (int j = 0; j < 8; j++) found += (tmp[j] >= 0);
    if (found == 8) for (int j = 0; j < 8; j++) ix[j] = tmp[j];

    const float* X      = (const float*)d_in[ix[0]];
    const int*   adj_w  = (const int*)d_in[ix[1]];
    const float* W_in   = (const float*)d_in[ix[2]];
    const float* b_in   = (const float*)d_in[ix[3]];
    const float* W_comb = (const float*)d_in[ix[4]];
    const float* b_comb = (const float*)d_in[ix[5]];
    const float* W_out  = (const float*)d_in[ix[6]];
    const float* b_out  = (const float*)d_in[ix[7]];
    float* out = (float*)d_out;

    // ws layout (bytes), total ~41.8MB
    char* base = (char*)d_ws;
    int*      deg      = (int*)(base + 0);
    int*      row_ptr  = (int*)(base + 200000);
    int*      cursor   = (int*)(base + 400004);
    float*    inv_deg  = (float*)(base + 600004);
    int*      edge_src = (int*)(base + 800008);
    _Float16* WinT     = (_Float16*)(base + 3200016);
    _Float16* WcombT   = (_Float16*)(base + 3232784);
    _Float16* WoutT    = (_Float16*)(base + 3363856);
    _Float16* hA       = (_Float16*)(base + 3376144);
    _Float16* hB       = (_Float16*)(base + 16176144);
    _Float16* msg      = (_Float16*)(base + 28976144);
    int*      bsum     = (int*)hA;  // hA written only after bsum consumed

    hipMemsetAsync(deg, 0, N_NODES * sizeof(int), stream);
    k_count_prep<<<COUNT_B + WPREP_B, 256, 0, stream>>>(adj_w, deg, W_in, W_comb, W_out,
                                                        WinT, WcombT, WoutT);
    k_scan1<<<NBLK, 1024, 0, stream>>>(deg, row_ptr, bsum);
    k_scan23<<<NBLK, 1024, 0, stream>>>(deg, row_ptr, bsum, cursor, inv_deg);
    k_fill_in<<<COUNT_B + IN_B, 256, 0, stream>>>(adj_w, cursor, edge_src, X, WinT, b_in, hA);

    k_gather<<<2048, 256, 0, stream>>>((const uint2*)hA, (uint2*)msg, row_ptr, edge_src, inv_deg);
    k_layer<<<782, 256, 0, stream>>>(hA, msg, WcombT, b_comb, hB);

    k_gather<<<2048, 256, 0, stream>>>((const uint2*)hB, (uint2*)msg, row_ptr, edge_src, inv_deg);
    k_layer_out<<<782, 256, 0, stream>>>(hB, msg, WcombT + 32768, b_comb + 128,
                                         WoutT, b_out, out);
}

// Round 2
// 254.827 us; speedup vs baseline: 1.1944x; 1.0723x over previous
//
#include <hip/hip_runtime.h>
#include <hip/hip_fp16.h>

#define N_NODES 50000
#define N_EDGES 600000
#define NBLK 49  // ceil(50000/1024)

typedef unsigned int u32;
typedef _Float16 v8h __attribute__((ext_vector_type(8)));
typedef _Float16 v4h __attribute__((ext_vector_type(4)));
typedef float v4f __attribute__((ext_vector_type(4)));

__device__ __forceinline__ float2 h2f2(u32 u) {
    __half2 h = *(__half2*)&u;
    return __half22float2(h);
}

// ---------------- adj layout detection (int64 vs int32), computed per-wave ----------------
__device__ __forceinline__ int calc_mode(const int* __restrict__ adj_w) {
    // int64 iff the high words of the first 64 entries are all zero
    int l = threadIdx.x & 63;
    unsigned long long b = __ballot(adj_w[2 * l + 1] != 0);
    return (b == 0ull) ? 1 : 0;
}
__device__ __forceinline__ int adj_to(const int* a, int m, int e) {
    return m ? a[4 * e + 2] : a[2 * e + 1];
}
__device__ __forceinline__ int adj_fro(const int* a, int m, int e) {
    return m ? a[4 * e] : a[2 * e];
}

#define CNT_B   293    // ceil(600000/(256*8)); 8 edges per thread
#define WPREP_B 344    // ceil(88064/256)
#define IN_B    1563   // ceil(50000/32)

// ---- merged: edge count (atomic, keeps rank) + weight transpose/convert ----
__global__ void k_count_prep(const int* __restrict__ adj_w, int* __restrict__ deg,
                             int* __restrict__ rank,
                             const float* __restrict__ W_in,
                             const float* __restrict__ W_comb,
                             const float* __restrict__ W_out,
                             _Float16* __restrict__ WinT,
                             _Float16* __restrict__ WcombT,
                             _Float16* __restrict__ WoutT) {
    if (blockIdx.x < CNT_B) {
        int m = calc_mode(adj_w);
        int base = blockIdx.x * 2048 + threadIdx.x;
        int to[8], r[8];
#pragma unroll
        for (int i = 0; i < 8; i++) {
            int e = base + i * 256;
            to[i] = (e < N_EDGES) ? adj_to(adj_w, m, e) : -1;
        }
#pragma unroll
        for (int i = 0; i < 8; i++)
            if (to[i] >= 0) r[i] = atomicAdd(&deg[to[i]], 1);
#pragma unroll
        for (int i = 0; i < 8; i++) {
            int e = base + i * 256;
            if (e < N_EDGES) rank[e] = r[i];
        }
        return;
    }
    int idx = (blockIdx.x - CNT_B) * 256 + threadIdx.x;
    if (idx < 16384) {
        int n = idx & 127, k = idx >> 7;
        WinT[n * 128 + k] = (_Float16)W_in[k * 128 + n];
    } else if (idx < 16384 + 65536) {
        int j = idx - 16384;
        int l = j >> 15, r = j & 32767;
        int n = r & 127, k = r >> 7;
        WcombT[l * 32768 + n * 256 + k] = (_Float16)W_comb[l * 32768 + k * 128 + n];
    } else if (idx < 16384 + 65536 + 6144) {
        int j = idx - 81920;
        int n = j >> 7, k = j & 127;
        WoutT[n * 128 + k] = (n < 40) ? (_Float16)W_out[k * 40 + n] : (_Float16)0.f;
    }
}

// ---------------- CSR scan ----------------
__global__ void k_scan1(const int* __restrict__ deg, int* __restrict__ row_ptr,
                        int* __restrict__ bsum) {
    __shared__ int s[1024];
    int tid = threadIdx.x, i = blockIdx.x * 1024 + tid;
    int v = (i < N_NODES) ? deg[i] : 0;
    s[tid] = v;
    __syncthreads();
    for (int off = 1; off < 1024; off <<= 1) {
        int t = (tid >= off) ? s[tid - off] : 0;
        __syncthreads();
        s[tid] += t;
        __syncthreads();
    }
    if (i < N_NODES) row_ptr[i] = s[tid] - v;
    if (tid == 1023) bsum[blockIdx.x] = s[1023];
}

// ---- merged scan2+scan3: each block reduces its own block-prefix of bsum ----
__global__ void k_scan23(const int* __restrict__ deg, int* __restrict__ row_ptr,
                         const int* __restrict__ bsum, float* __restrict__ inv_deg) {
    __shared__ int sbase;
    int tid = threadIdx.x;
    if (tid < 64) {
        int v = (tid < NBLK && tid < (int)blockIdx.x) ? bsum[tid] : 0;
#pragma unroll
        for (int off = 32; off > 0; off >>= 1) v += __shfl_down(v, off);
        if (tid == 0) sbase = v;
    }
    __syncthreads();
    int i = blockIdx.x * 1024 + tid;
    if (i < N_NODES) {
        row_ptr[i] = row_ptr[i] + sbase;
        inv_deg[i] = 1.0f / fmaxf((float)deg[i], 1.0f);
    }
    if (i == 0) row_ptr[N_NODES] = N_EDGES;
}

// ---- merged: atomic-free CSR fill (rank trick) + input GEMM h = relu(X @ W_in + b) ----
// blocks [0,CNT_B): fill; blocks [CNT_B, CNT_B+IN_B): MFMA M-tile 32, K=128, N=128
__global__ __launch_bounds__(256, 2) void k_fill_in(const int* __restrict__ adj_w,
                                                    const int* __restrict__ row_ptr,
                                                    const int* __restrict__ rank,
                                                    int* __restrict__ edge_src,
                                                    const float* __restrict__ X,
                                                    const _Float16* __restrict__ WT,
                                                    const float* __restrict__ bias,
                                                    _Float16* __restrict__ h) {
    __shared__ __align__(16) _Float16 xs[32][136];
    if (blockIdx.x < CNT_B) {
        int m = calc_mode(adj_w);
        int base = blockIdx.x * 2048 + threadIdx.x;
        int to[8], fro[8], rk[8];
#pragma unroll
        for (int i = 0; i < 8; i++) {
            int e = base + i * 256;
            if (e < N_EDGES) {
                to[i] = adj_to(adj_w, m, e);
                fro[i] = adj_fro(adj_w, m, e);
                rk[i] = rank[e];
            } else {
                to[i] = -1;
            }
        }
#pragma unroll
        for (int i = 0; i < 8; i++)
            if (to[i] >= 0) edge_src[row_ptr[to[i]] + rk[i]] = fro[i];
        return;
    }
    const int t0 = threadIdx.x, w = t0 >> 6, l = t0 & 63;
    const int R0 = (blockIdx.x - CNT_B) * 32;
    const float4* X4 = (const float4*)X;
#pragma unroll
    for (int i = 0; i < 4; i++) {
        int idx = i * 256 + t0;
        int row = idx >> 5, c4 = idx & 31;
        int rr = R0 + row;
        if (rr > N_NODES - 1) rr = N_NODES - 1;
        float4 v = X4[(size_t)rr * 32 + c4];
        v4h hv = {(_Float16)v.x, (_Float16)v.y, (_Float16)v.z, (_Float16)v.w};
        *(v4h*)&xs[row][c4 * 4] = hv;
    }
    const int ch = w & 1, rh = w >> 1;
    v8h wf[4][4];
#pragma unroll
    for (int t = 0; t < 4; t++)
#pragma unroll
        for (int s = 0; s < 4; s++) {
            int n = ch * 64 + t * 16 + (l & 15);
            int k = s * 32 + (l >> 4) * 8;
            wf[t][s] = *(const v8h*)&WT[n * 128 + k];
        }
    v4f acc[4];
#pragma unroll
    for (int t = 0; t < 4; t++) acc[t] = (v4f){0.f, 0.f, 0.f, 0.f};
    __syncthreads();
#pragma unroll
    for (int s = 0; s < 4; s++) {
        v8h a = *(const v8h*)&xs[rh * 16 + (l & 15)][s * 32 + (l >> 4) * 8];
#pragma unroll
        for (int t = 0; t < 4; t++)
            acc[t] = __builtin_amdgcn_mfma_f32_16x16x32_f16(a, wf[t][s], acc[t], 0, 0, 0);
    }
#pragma unroll
    for (int t = 0; t < 4; t++) {
        int col = ch * 64 + t * 16 + (l & 15);
        float b = bias[col];
#pragma unroll
        for (int i = 0; i < 4; i++) {
            int row = R0 + rh * 16 + (l >> 4) * 4 + i;
            if (row < N_NODES)
                h[(size_t)row * 128 + col] = (_Float16)fmaxf(acc[t][i] + b, 0.f);
        }
    }
}

// ---- gather v2: dual-edge 8B loads. lanes 0-31 = even edge, 32-63 = odd edge ----
__global__ __launch_bounds__(256) void k_gather(const uint2* __restrict__ h4,
                                                uint2* __restrict__ msg4,
                                                const int* __restrict__ row_ptr,
                                                const int* __restrict__ edge_src,
                                                const float* __restrict__ inv_deg) {
    const int w = threadIdx.x >> 6, l = threadIdx.x & 63;
    const int half = l >> 5, c = l & 31;  // c: which 8B chunk of the 256B row
    const int wid = blockIdx.x * 4 + w, nw = gridDim.x * 4;
    for (int row = wid; row < N_NODES; row += nw) {
        const int e0 = row_ptr[row], e1 = row_ptr[row + 1];
        float a0 = 0.f, a1 = 0.f, a2 = 0.f, a3 = 0.f;
        for (int bse = e0; bse < e1; bse += 8) {
            uint2 v[4];
#pragma unroll
            for (int i = 0; i < 4; i++) {
                int ee = bse + 2 * i + half;
                int idx = (ee < e1) ? ee : (e1 - 1);
                v[i] = h4[(size_t)edge_src[idx] * 32 + c];
            }
#pragma unroll
            for (int i = 0; i < 4; i++) {
                if (bse + 2 * i + half < e1) {
                    float2 f0 = h2f2(v[i].x), f1 = h2f2(v[i].y);
                    a0 += f0.x;
                    a1 += f0.y;
                    a2 += f1.x;
                    a3 += f1.y;
                }
            }
        }
        a0 += __shfl_xor(a0, 32);
        a1 += __shfl_xor(a1, 32);
        a2 += __shfl_xor(a2, 32);
        a3 += __shfl_xor(a3, 32);
        if (half == 0) {
            const float inv = inv_deg[row];
            __half2 o0 = __floats2half2_rn(a0 * inv, a1 * inv);
            __half2 o1 = __floats2half2_rn(a2 * inv, a3 * inv);
            uint2 o;
            o.x = *(u32*)&o0;
            o.y = *(u32*)&o1;
            msg4[(size_t)row * 32 + c] = o;
        }
    }
}

// ---- MFMA layer GEMM: hout = relu([h|msg] @ Wc + b); M-tile 64, K=256, N=128 ----
__global__ __launch_bounds__(256, 2) void k_layer(const _Float16* __restrict__ hin,
                                                  const _Float16* __restrict__ msg,
                                                  const _Float16* __restrict__ WT,
                                                  const float* __restrict__ bias,
                                                  _Float16* __restrict__ hout) {
    __shared__ __align__(16) _Float16 xs[64][264];  // 33.8KB
    const int t0 = threadIdx.x, w = t0 >> 6, l = t0 & 63;
    const int R0 = blockIdx.x * 64;
    const uint4* h4 = (const uint4*)hin;
    const uint4* m4 = (const uint4*)msg;
#pragma unroll
    for (int i = 0; i < 8; i++) {
        int idx = i * 256 + t0;
        int row = idx >> 5, c16 = idx & 31;
        int rr = R0 + row;
        if (rr > N_NODES - 1) rr = N_NODES - 1;
        uint4 v = (c16 < 16) ? h4[(size_t)rr * 16 + c16] : m4[(size_t)rr * 16 + (c16 - 16)];
        *(uint4*)&xs[row][c16 * 8] = v;
    }
    const int ch = w & 1, rh = w >> 1;
    v8h wf[4][8];
#pragma unroll
    for (int t = 0; t < 4; t++)
#pragma unroll
        for (int s = 0; s < 8; s++) {
            int n = ch * 64 + t * 16 + (l & 15);
            int k = s * 32 + (l >> 4) * 8;
            wf[t][s] = *(const v8h*)&WT[n * 256 + k];
        }
    v4f acc[2][4];
#pragma unroll
    for (int sub = 0; sub < 2; sub++)
#pragma unroll
        for (int t = 0; t < 4; t++) acc[sub][t] = (v4f){0.f, 0.f, 0.f, 0.f};
    __syncthreads();
#pragma unroll
    for (int s = 0; s < 8; s++) {
#pragma unroll
        for (int sub = 0; sub < 2; sub++) {
            v8h a = *(const v8h*)&xs[rh * 32 + sub * 16 + (l & 15)][s * 32 + (l >> 4) * 8];
#pragma unroll
            for (int t = 0; t < 4; t++)
                acc[sub][t] = __builtin_amdgcn_mfma_f32_16x16x32_f16(a, wf[t][s], acc[sub][t], 0, 0, 0);
        }
    }
#pragma unroll
    for (int sub = 0; sub < 2; sub++)
#pragma unroll
        for (int t = 0; t < 4; t++) {
            int col = ch * 64 + t * 16 + (l & 15);
            float b = bias[col];
#pragma unroll
            for (int i = 0; i < 4; i++) {
                int row = R0 + rh * 32 + sub * 16 + (l >> 4) * 4 + i;
                if (row < N_NODES)
                    hout[(size_t)row * 128 + col] = (_Float16)fmaxf(acc[sub][t][i] + b, 0.f);
            }
        }
}

// ---- fused layer-2 + out: h2 = relu([h|msg] @ Wc + b) staged in LDS, then
// out = h2 @ W_out + b_out directly. Saves the 25.6MB hA round-trip. ----
__global__ __launch_bounds__(256, 2) void k_layer_out(const _Float16* __restrict__ hin,
                                                      const _Float16* __restrict__ msg,
                                                      const _Float16* __restrict__ WT,
                                                      const float* __restrict__ bias,
                                                      const _Float16* __restrict__ WoT,
                                                      const float* __restrict__ bias_o,
                                                      float* __restrict__ outp) {
    __shared__ __align__(16) _Float16 xs[64][264];
    const int t0 = threadIdx.x, w = t0 >> 6, l = t0 & 63;
    const int R0 = blockIdx.x * 64;
    const uint4* h4 = (const uint4*)hin;
    const uint4* m4 = (const uint4*)msg;
#pragma unroll
    for (int i = 0; i < 8; i++) {
        int idx = i * 256 + t0;
        int row = idx >> 5, c16 = idx & 31;
        int rr = R0 + row;
        if (rr > N_NODES - 1) rr = N_NODES - 1;
        uint4 v = (c16 < 16) ? h4[(size_t)rr * 16 + c16] : m4[(size_t)rr * 16 + (c16 - 16)];
        *(uint4*)&xs[row][c16 * 8] = v;
    }
    const int ch = w & 1, rh = w >> 1;
    v8h wf[4][8];
#pragma unroll
    for (int t = 0; t < 4; t++)
#pragma unroll
        for (int s = 0; s < 8; s++) {
            int n = ch * 64 + t * 16 + (l & 15);
            int k = s * 32 + (l >> 4) * 8;
            wf[t][s] = *(const v8h*)&WT[n * 256 + k];
        }
    v4f acc[2][4];
#pragma unroll
    for (int sub = 0; sub < 2; sub++)
#pragma unroll
        for (int t = 0; t < 4; t++) acc[sub][t] = (v4f){0.f, 0.f, 0.f, 0.f};
    __syncthreads();
#pragma unroll
    for (int s = 0; s < 8; s++) {
#pragma unroll
        for (int sub = 0; sub < 2; sub++) {
            v8h a = *(const v8h*)&xs[rh * 32 + sub * 16 + (l & 15)][s * 32 + (l >> 4) * 8];
#pragma unroll
            for (int t = 0; t < 4; t++)
                acc[sub][t] = __builtin_amdgcn_mfma_f32_16x16x32_f16(a, wf[t][s], acc[sub][t], 0, 0, 0);
        }
    }
    __syncthreads();  // all xs reads done; safe to overwrite with h2 tile
    _Float16* hs = &xs[0][0];  // reused as [64][136]
#pragma unroll
    for (int sub = 0; sub < 2; sub++)
#pragma unroll
        for (int t = 0; t < 4; t++) {
            int col = ch * 64 + t * 16 + (l & 15);
            float b = bias[col];
#pragma unroll
            for (int i = 0; i < 4; i++) {
                int lrow = rh * 32 + sub * 16 + (l >> 4) * 4 + i;
                hs[lrow * 136 + col] = (_Float16)fmaxf(acc[sub][t][i] + b, 0.f);
            }
        }
    v8h wo[3][4];
#pragma unroll
    for (int t = 0; t < 3; t++)
#pragma unroll
        for (int s = 0; s < 4; s++) {
            int n = t * 16 + (l & 15);
            int k = s * 32 + (l >> 4) * 8;
            wo[t][s] = *(const v8h*)&WoT[n * 128 + k];
        }
    v4f acc2[3];
#pragma unroll
    for (int t = 0; t < 3; t++) acc2[t] = (v4f){0.f, 0.f, 0.f, 0.f};
    __syncthreads();
#pragma unroll
    for (int s = 0; s < 4; s++) {
        v8h a = *(const v8h*)&hs[(w * 16 + (l & 15)) * 136 + s * 32 + (l >> 4) * 8];
#pragma unroll
        for (int t = 0; t < 3; t++)
            acc2[t] = __builtin_amdgcn_mfma_f32_16x16x32_f16(a, wo[t][s], acc2[t], 0, 0, 0);
    }
#pragma unroll
    for (int t = 0; t < 3; t++) {
        int col = t * 16 + (l & 15);
        if (col < 40) {
            float b = bias_o[col];
#pragma unroll
            for (int i = 0; i < 4; i++) {
                int row = R0 + w * 16 + (l >> 4) * 4 + i;
                if (row < N_NODES) outp[(size_t)row * 40 + col] = acc2[t][i] + b;
            }
        }
    }
}

extern "C" void kernel_launch(void* const* d_in, const int* in_sizes, int n_in,
                              void* d_out, int out_size, void* d_ws, size_t ws_size,
                              hipStream_t stream) {
    int ix[8] = {0, 1, 2, 3, 4, 5, 6, 7};
    int tmp[8] = {-1, -1, -1, -1, -1, -1, -1, -1};
    for (int i = 0; i < n_in && i < 8; i++) {
        switch (in_sizes[i]) {
            case 6400000: tmp[0] = i; break;
            case 1200000: case 2400000: tmp[1] = i; break;
            case 16384:   tmp[2] = i; break;
            case 128:     tmp[3] = i; break;
            case 65536:   tmp[4] = i; break;
            case 256:     tmp[5] = i; break;
            case 5120:    tmp[6] = i; break;
            case 40:      tmp[7] = i; break;
        }
    }
    int found = 0;
    for (int j = 0; j < 8; j++) found += (tmp[j] >= 0);
    if (found == 8) for (int j = 0; j < 8; j++) ix[j] = tmp[j];

    const float* X      = (const float*)d_in[ix[0]];
    const int*   adj_w  = (const int*)d_in[ix[1]];
    const float* W_in   = (const float*)d_in[ix[2]];
    const float* b_in   = (const float*)d_in[ix[3]];
    const float* W_comb = (const float*)d_in[ix[4]];
    const float* b_comb = (const float*)d_in[ix[5]];
    const float* W_out  = (const float*)d_in[ix[6]];
    const float* b_out  = (const float*)d_in[ix[7]];
    float* out = (float*)d_out;

    // ws layout (bytes), total ~44MB
    char* base = (char*)d_ws;
    int*      deg      = (int*)(base + 0);          // 200000
    int*      row_ptr  = (int*)(base + 200000);     // 200004
    int*      rank     = (int*)(base + 400004);     // 2400000
    float*    inv_deg  = (float*)(base + 2800004);  // 200000
    int*      edge_src = (int*)(base + 3000008);    // 2400000
    _Float16* WinT     = (_Float16*)(base + 5400016);
    _Float16* WcombT   = (_Float16*)(base + 5432784);
    _Float16* WoutT    = (_Float16*)(base + 5563856);
    _Float16* hA       = (_Float16*)(base + 5576144);
    _Float16* hB       = (_Float16*)(base + 18376144);
    _Float16* msg      = (_Float16*)(base + 31176144);
    int*      bsum     = (int*)hA;  // hA written only after bsum consumed

    hipMemsetAsync(deg, 0, N_NODES * sizeof(int), stream);
    k_count_prep<<<CNT_B + WPREP_B, 256, 0, stream>>>(adj_w, deg, rank, W_in, W_comb, W_out,
                                                      WinT, WcombT, WoutT);
    k_scan1<<<NBLK, 1024, 0, stream>>>(deg, row_ptr, bsum);
    k_scan23<<<NBLK, 1024, 0, stream>>>(deg, row_ptr, bsum, inv_deg);
    k_fill_in<<<CNT_B + IN_B, 256, 0, stream>>>(adj_w, row_ptr, rank, edge_src,
                                                X, WinT, b_in, hA);

    k_gather<<<2048, 256, 0, stream>>>((const uint2*)hA, (uint2*)msg, row_ptr, edge_src, inv_deg);
    k_layer<<<782, 256, 0, stream>>>(hA, msg, WcombT, b_comb, hB);

    k_gather<<<2048, 256, 0, stream>>>((const uint2*)hB, (uint2*)msg, row_ptr, edge_src, inv_deg);
    k_layer_out<<<782, 256, 0, stream>>>(hB, msg, WcombT + 32768, b_comb + 128,
                                         WoutT, b_out, out);
}

// Round 3
// 243.626 us; speedup vs baseline: 1.2493x; 1.0460x over previous
//
#include <hip/hip_runtime.h>
#include <hip/hip_fp16.h>

#define N_NODES 50000
#define N_EDGES 600000
#define NBLK 49  // ceil(50000/1024)

typedef unsigned int u32;
typedef _Float16 v8h __attribute__((ext_vector_type(8)));
typedef _Float16 v4h __attribute__((ext_vector_type(4)));
typedef float v4f __attribute__((ext_vector_type(4)));

__device__ __forceinline__ float2 h2f2(u32 u) {
    __half2 h = *(__half2*)&u;
    return __half22float2(h);
}

// ---------------- adj layout detection (int64 vs int32), computed per-wave ----------------
__device__ __forceinline__ int calc_mode(const int* __restrict__ adj_w) {
    // int64 iff the high words of the first 64 entries are all zero
    int l = threadIdx.x & 63;
    unsigned long long b = __ballot(adj_w[2 * l + 1] != 0);
    return (b == 0ull) ? 1 : 0;
}
// vectorized edge load: int64 mode = one uint4 (fro=lo(x), to=lo(z)); int32 = uint2
__device__ __forceinline__ void load_edge(const int* __restrict__ a, int m, int e,
                                          int& fro, int& to) {
    if (m) {
        uint4 v = ((const uint4*)a)[e];
        fro = (int)v.x;
        to = (int)v.z;
    } else {
        uint2 v = ((const uint2*)a)[e];
        fro = (int)v.x;
        to = (int)v.y;
    }
}

#define CNT_B   293    // ceil(600000/(256*8)); 8 edges per thread
#define WPREP_B 344    // ceil(88064/256)
#define IN_B    1563   // ceil(50000/32)

// ---- merged: edge count (atomic, keeps rank) + weight transpose/convert ----
__global__ void k_count_prep(const int* __restrict__ adj_w, int* __restrict__ deg,
                             int* __restrict__ rank,
                             const float* __restrict__ W_in,
                             const float* __restrict__ W_comb,
                             const float* __restrict__ W_out,
                             _Float16* __restrict__ WinT,
                             _Float16* __restrict__ WcombT,
                             _Float16* __restrict__ WoutT) {
    if (blockIdx.x < CNT_B) {
        int m = calc_mode(adj_w);
        int base = blockIdx.x * 2048 + threadIdx.x;
        int to[8], r[8];
#pragma unroll
        for (int i = 0; i < 8; i++) {
            int e = base + i * 256;
            if (e < N_EDGES) {
                int f;
                load_edge(adj_w, m, e, f, to[i]);
            } else {
                to[i] = -1;
            }
        }
#pragma unroll
        for (int i = 0; i < 8; i++)
            if (to[i] >= 0) r[i] = atomicAdd(&deg[to[i]], 1);
#pragma unroll
        for (int i = 0; i < 8; i++) {
            int e = base + i * 256;
            if (e < N_EDGES) rank[e] = r[i];
        }
        return;
    }
    int idx = (blockIdx.x - CNT_B) * 256 + threadIdx.x;
    if (idx < 16384) {
        int n = idx & 127, k = idx >> 7;
        WinT[n * 128 + k] = (_Float16)W_in[k * 128 + n];
    } else if (idx < 16384 + 65536) {
        int j = idx - 16384;
        int l = j >> 15, r = j & 32767;
        int n = r & 127, k = r >> 7;
        WcombT[l * 32768 + n * 256 + k] = (_Float16)W_comb[l * 32768 + k * 128 + n];
    } else if (idx < 16384 + 65536 + 6144) {
        int j = idx - 81920;
        int n = j >> 7, k = j & 127;
        WoutT[n * 128 + k] = (n < 40) ? (_Float16)W_out[k * 40 + n] : (_Float16)0.f;
    }
}

// ---- single-kernel CSR scan: per-block LDS scan + 49-block lookback ----
// bsync[] must be zeroed. All 49 blocks co-resident on 256 CUs -> no deadlock.
__global__ void k_scan(const int* __restrict__ deg, int* __restrict__ row_ptr,
                       float* __restrict__ inv_deg, int* __restrict__ bsync) {
    __shared__ int s[1024];
    __shared__ int sbase;
    const int tid = threadIdx.x, b = blockIdx.x;
    const int i = b * 1024 + tid;
    int v = (i < N_NODES) ? deg[i] : 0;
    s[tid] = v;
    __syncthreads();
    for (int off = 1; off < 1024; off <<= 1) {
        int t = (tid >= off) ? s[tid - off] : 0;
        __syncthreads();
        s[tid] += t;
        __syncthreads();
    }
    if (tid == 1023)
        __hip_atomic_store(&bsync[b], 0x40000000 | s[1023], __ATOMIC_RELEASE,
                           __HIP_MEMORY_SCOPE_AGENT);
    if (tid < 64) {
        int acc = 0;
        if (tid < b) {
            int x;
            do {
                x = __hip_atomic_load(&bsync[tid], __ATOMIC_ACQUIRE,
                                      __HIP_MEMORY_SCOPE_AGENT);
            } while (x < 0x40000000);
            acc = x & 0x3fffffff;
        }
#pragma unroll
        for (int off = 32; off > 0; off >>= 1) acc += __shfl_down(acc, off);
        if (tid == 0) sbase = acc;
    }
    __syncthreads();
    if (i < N_NODES) {
        row_ptr[i] = sbase + s[tid] - v;  // exclusive prefix
        inv_deg[i] = 1.0f / fmaxf((float)v, 1.0f);
    }
    if (i == 0) row_ptr[N_NODES] = N_EDGES;
}

// ---- merged: atomic-free CSR fill (rank trick) + input GEMM h = relu(X @ W_in + b) ----
// blocks [0,CNT_B): fill; blocks [CNT_B, CNT_B+IN_B): MFMA M-tile 32, K=128, N=128
__global__ __launch_bounds__(256, 2) void k_fill_in(const int* __restrict__ adj_w,
                                                    const int* __restrict__ row_ptr,
                                                    const int* __restrict__ rank,
                                                    int* __restrict__ edge_src,
                                                    const float* __restrict__ X,
                                                    const _Float16* __restrict__ WT,
                                                    const float* __restrict__ bias,
                                                    _Float16* __restrict__ h) {
    __shared__ __align__(16) _Float16 xs[32][136];
    if (blockIdx.x < CNT_B) {
        int m = calc_mode(adj_w);
        int base = blockIdx.x * 2048 + threadIdx.x;
        int to[8], fro[8], rk[8];
#pragma unroll
        for (int i = 0; i < 8; i++) {
            int e = base + i * 256;
            if (e < N_EDGES) {
                load_edge(adj_w, m, e, fro[i], to[i]);
                rk[i] = rank[e];
            } else {
                to[i] = -1;
            }
        }
#pragma unroll
        for (int i = 0; i < 8; i++)
            if (to[i] >= 0) edge_src[row_ptr[to[i]] + rk[i]] = fro[i];
        return;
    }
    const int t0 = threadIdx.x, w = t0 >> 6, l = t0 & 63;
    const int R0 = (blockIdx.x - CNT_B) * 32;
    const float4* X4 = (const float4*)X;
#pragma unroll
    for (int i = 0; i < 4; i++) {
        int idx = i * 256 + t0;
        int row = idx >> 5, c4 = idx & 31;
        int rr = R0 + row;
        if (rr > N_NODES - 1) rr = N_NODES - 1;
        float4 v = X4[(size_t)rr * 32 + c4];
        v4h hv = {(_Float16)v.x, (_Float16)v.y, (_Float16)v.z, (_Float16)v.w};
        *(v4h*)&xs[row][c4 * 4] = hv;
    }
    const int ch = w & 1, rh = w >> 1;
    v8h wf[4][4];
#pragma unroll
    for (int t = 0; t < 4; t++)
#pragma unroll
        for (int s = 0; s < 4; s++) {
            int n = ch * 64 + t * 16 + (l & 15);
            int k = s * 32 + (l >> 4) * 8;
            wf[t][s] = *(const v8h*)&WT[n * 128 + k];
        }
    v4f acc[4];
#pragma unroll
    for (int t = 0; t < 4; t++) acc[t] = (v4f){0.f, 0.f, 0.f, 0.f};
    __syncthreads();
#pragma unroll
    for (int s = 0; s < 4; s++) {
        v8h a = *(const v8h*)&xs[rh * 16 + (l & 15)][s * 32 + (l >> 4) * 8];
#pragma unroll
        for (int t = 0; t < 4; t++)
            acc[t] = __builtin_amdgcn_mfma_f32_16x16x32_f16(a, wf[t][s], acc[t], 0, 0, 0);
    }
#pragma unroll
    for (int t = 0; t < 4; t++) {
        int col = ch * 64 + t * 16 + (l & 15);
        float b = bias[col];
#pragma unroll
        for (int i = 0; i < 4; i++) {
            int row = R0 + rh * 16 + (l >> 4) * 4 + i;
            if (row < N_NODES)
                h[(size_t)row * 128 + col] = (_Float16)fmaxf(acc[t][i] + b, 0.f);
        }
    }
}

// ---- gather v3: 16-lane groups x uint4 loads; 16 edges/iter; row_ptr prefetch ----
__global__ __launch_bounds__(256) void k_gather(const uint4* __restrict__ h16,
                                                uint4* __restrict__ msg16,
                                                const int* __restrict__ row_ptr,
                                                const int* __restrict__ edge_src,
                                                const float* __restrict__ inv_deg) {
    const int w = threadIdx.x >> 6, l = threadIdx.x & 63;
    const int grp = l >> 4, c = l & 15;  // c: which 16B chunk of the 256B row
    const int wid = blockIdx.x * 4 + w, nw = gridDim.x * 4;
    if (wid >= N_NODES) return;
    int pe0 = row_ptr[wid], pe1 = row_ptr[wid + 1];
    for (int row = wid; row < N_NODES; row += nw) {
        const int e0 = pe0, e1 = pe1;
        const float inv = inv_deg[row];  // issued early, hidden under gather
        const int nrow = row + nw;
        if (nrow < N_NODES) {
            pe0 = row_ptr[nrow];
            pe1 = row_ptr[nrow + 1];
        }
        float a[8];
#pragma unroll
        for (int k = 0; k < 8; k++) a[k] = 0.f;
        for (int bse = e0; bse < e1; bse += 16) {
            uint4 v[4];
            int ok[4];
#pragma unroll
            for (int i = 0; i < 4; i++) {
                int ee = bse + 4 * i + grp;
                ok[i] = (ee < e1);
                int idx = ok[i] ? ee : (e1 - 1);
                v[i] = h16[(size_t)edge_src[idx] * 16 + c];
            }
#pragma unroll
            for (int i = 0; i < 4; i++) {
                if (ok[i]) {
                    u32 u[4] = {v[i].x, v[i].y, v[i].z, v[i].w};
#pragma unroll
                    for (int k = 0; k < 4; k++) {
                        float2 f = h2f2(u[k]);
                        a[2 * k] += f.x;
                        a[2 * k + 1] += f.y;
                    }
                }
            }
        }
#pragma unroll
        for (int k = 0; k < 8; k++) {
            a[k] += __shfl_xor(a[k], 16);
            a[k] += __shfl_xor(a[k], 32);
        }
        if (grp == 0) {
            __half2 o0 = __floats2half2_rn(a[0] * inv, a[1] * inv);
            __half2 o1 = __floats2half2_rn(a[2] * inv, a[3] * inv);
            __half2 o2 = __floats2half2_rn(a[4] * inv, a[5] * inv);
            __half2 o3 = __floats2half2_rn(a[6] * inv, a[7] * inv);
            uint4 o;
            o.x = *(u32*)&o0;
            o.y = *(u32*)&o1;
            o.z = *(u32*)&o2;
            o.w = *(u32*)&o3;
            msg16[(size_t)row * 16 + c] = o;
        }
    }
}

// ---- MFMA layer GEMM: hout = relu([h|msg] @ Wc + b); M-tile 64, K=256, N=128 ----
__global__ __launch_bounds__(256, 2) void k_layer(const _Float16* __restrict__ hin,
                                                  const _Float16* __restrict__ msg,
                                                  const _Float16* __restrict__ WT,
                                                  const float* __restrict__ bias,
                                                  _Float16* __restrict__ hout) {
    __shared__ __align__(16) _Float16 xs[64][264];  // 33.8KB
    const int t0 = threadIdx.x, w = t0 >> 6, l = t0 & 63;
    const int R0 = blockIdx.x * 64;
    const uint4* h4 = (const uint4*)hin;
    const uint4* m4 = (const uint4*)msg;
#pragma unroll
    for (int i = 0; i < 8; i++) {
        int idx = i * 256 + t0;
        int row = idx >> 5, c16 = idx & 31;
        int rr = R0 + row;
        if (rr > N_NODES - 1) rr = N_NODES - 1;
        uint4 v = (c16 < 16) ? h4[(size_t)rr * 16 + c16] : m4[(size_t)rr * 16 + (c16 - 16)];
        *(uint4*)&xs[row][c16 * 8] = v;
    }
    const int ch = w & 1, rh = w >> 1;
    v8h wf[4][8];
#pragma unroll
    for (int t = 0; t < 4; t++)
#pragma unroll
        for (int s = 0; s < 8; s++) {
            int n = ch * 64 + t * 16 + (l & 15);
            int k = s * 32 + (l >> 4) * 8;
            wf[t][s] = *(const v8h*)&WT[n * 256 + k];
        }
    v4f acc[2][4];
#pragma unroll
    for (int sub = 0; sub < 2; sub++)
#pragma unroll
        for (int t = 0; t < 4; t++) acc[sub][t] = (v4f){0.f, 0.f, 0.f, 0.f};
    __syncthreads();
#pragma unroll
    for (int s = 0; s < 8; s++) {
#pragma unroll
        for (int sub = 0; sub < 2; sub++) {
            v8h a = *(const v8h*)&xs[rh * 32 + sub * 16 + (l & 15)][s * 32 + (l >> 4) * 8];
#pragma unroll
            for (int t = 0; t < 4; t++)
                acc[sub][t] = __builtin_amdgcn_mfma_f32_16x16x32_f16(a, wf[t][s], acc[sub][t], 0, 0, 0);
        }
    }
#pragma unroll
    for (int sub = 0; sub < 2; sub++)
#pragma unroll
        for (int t = 0; t < 4; t++) {
            int col = ch * 64 + t * 16 + (l & 15);
            float b = bias[col];
#pragma unroll
            for (int i = 0; i < 4; i++) {
                int row = R0 + rh * 32 + sub * 16 + (l >> 4) * 4 + i;
                if (row < N_NODES)
                    hout[(size_t)row * 128 + col] = (_Float16)fmaxf(acc[sub][t][i] + b, 0.f);
            }
        }
}

// ---- fused layer-2 + out: h2 = relu([h|msg] @ Wc + b) staged in LDS, then
// out = h2 @ W_out + b_out directly. Saves the 25.6MB hA round-trip. ----
__global__ __launch_bounds__(256, 2) void k_layer_out(const _Float16* __restrict__ hin,
                                                      const _Float16* __restrict__ msg,
                                                      const _Float16* __restrict__ WT,
                                                      const float* __restrict__ bias,
                                                      const _Float16* __restrict__ WoT,
                                                      const float* __restrict__ bias_o,
                                                      float* __restrict__ outp) {
    __shared__ __align__(16) _Float16 xs[64][264];
    const int t0 = threadIdx.x, w = t0 >> 6, l = t0 & 63;
    const int R0 = blockIdx.x * 64;
    const uint4* h4 = (const uint4*)hin;
    const uint4* m4 = (const uint4*)msg;
#pragma unroll
    for (int i = 0; i < 8; i++) {
        int idx = i * 256 + t0;
        int row = idx >> 5, c16 = idx & 31;
        int rr = R0 + row;
        if (rr > N_NODES - 1) rr = N_NODES - 1;
        uint4 v = (c16 < 16) ? h4[(size_t)rr * 16 + c16] : m4[(size_t)rr * 16 + (c16 - 16)];
        *(uint4*)&xs[row][c16 * 8] = v;
    }
    const int ch = w & 1, rh = w >> 1;
    v8h wf[4][8];
#pragma unroll
    for (int t = 0; t < 4; t++)
#pragma unroll
        for (int s = 0; s < 8; s++) {
            int n = ch * 64 + t * 16 + (l & 15);
            int k = s * 32 + (l >> 4) * 8;
            wf[t][s] = *(const v8h*)&WT[n * 256 + k];
        }
    v4f acc[2][4];
#pragma unroll
    for (int sub = 0; sub < 2; sub++)
#pragma unroll
        for (int t = 0; t < 4; t++) acc[sub][t] = (v4f){0.f, 0.f, 0.f, 0.f};
    __syncthreads();
#pragma unroll
    for (int s = 0; s < 8; s++) {
#pragma unroll
        for (int sub = 0; sub < 2; sub++) {
            v8h a = *(const v8h*)&xs[rh * 32 + sub * 16 + (l & 15)][s * 32 + (l >> 4) * 8];
#pragma unroll
            for (int t = 0; t < 4; t++)
                acc[sub][t] = __builtin_amdgcn_mfma_f32_16x16x32_f16(a, wf[t][s], acc[sub][t], 0, 0, 0);
        }
    }
    __syncthreads();  // all xs reads done; safe to overwrite with h2 tile
    _Float16* hs = &xs[0][0];  // reused as [64][136]
#pragma unroll
    for (int sub = 0; sub < 2; sub++)
#pragma unroll
        for (int t = 0; t < 4; t++) {
            int col = ch * 64 + t * 16 + (l & 15);
            float b = bias[col];
#pragma unroll
            for (int i = 0; i < 4; i++) {
                int lrow = rh * 32 + sub * 16 + (l >> 4) * 4 + i;
                hs[lrow * 136 + col] = (_Float16)fmaxf(acc[sub][t][i] + b, 0.f);
            }
        }
    v8h wo[3][4];
#pragma unroll
    for (int t = 0; t < 3; t++)
#pragma unroll
        for (int s = 0; s < 4; s++) {
            int n = t * 16 + (l & 15);
            int k = s * 32 + (l >> 4) * 8;
            wo[t][s] = *(const v8h*)&WoT[n * 128 + k];
        }
    v4f acc2[3];
#pragma unroll
    for (int t = 0; t < 3; t++) acc2[t] = (v4f){0.f, 0.f, 0.f, 0.f};
    __syncthreads();
#pragma unroll
    for (int s = 0; s < 4; s++) {
        v8h a = *(const v8h*)&hs[(w * 16 + (l & 15)) * 136 + s * 32 + (l >> 4) * 8];
#pragma unroll
        for (int t = 0; t < 3; t++)
            acc2[t] = __builtin_amdgcn_mfma_f32_16x16x32_f16(a, wo[t][s], acc2[t], 0, 0, 0);
    }
#pragma unroll
    for (int t = 0; t < 3; t++) {
        int col = t * 16 + (l & 15);
        if (col < 40) {
            float b = bias_o[col];
#pragma unroll
            for (int i = 0; i < 4; i++) {
                int row = R0 + w * 16 + (l >> 4) * 4 + i;
                if (row < N_NODES) outp[(size_t)row * 40 + col] = acc2[t][i] + b;
            }
        }
    }
}

extern "C" void kernel_launch(void* const* d_in, const int* in_sizes, int n_in,
                              void* d_out, int out_size, void* d_ws, size_t ws_size,
                              hipStream_t stream) {
    int ix[8] = {0, 1, 2, 3, 4, 5, 6, 7};
    int tmp[8] = {-1, -1, -1, -1, -1, -1, -1, -1};
    for (int i = 0; i < n_in && i < 8; i++) {
        switch (in_sizes[i]) {
            case 6400000: tmp[0] = i; break;
            case 1200000: case 2400000: tmp[1] = i; break;
            case 16384:   tmp[2] = i; break;
            case 128:     tmp[3] = i; break;
            case 65536:   tmp[4] = i; break;
            case 256:     tmp[5] = i; break;
            case 5120:    tmp[6] = i; break;
            case 40:      tmp[7] = i; break;
        }
    }
    int found = 0;
    for (int j = 0; j < 8; j++) found += (tmp[j] >= 0);
    if (found == 8) for (int j = 0; j < 8; j++) ix[j] = tmp[j];

    const float* X      = (const float*)d_in[ix[0]];
    const int*   adj_w  = (const int*)d_in[ix[1]];
    const float* W_in   = (const float*)d_in[ix[2]];
    const float* b_in   = (const float*)d_in[ix[3]];
    const float* W_comb = (const float*)d_in[ix[4]];
    const float* b_comb = (const float*)d_in[ix[5]];
    const float* W_out  = (const float*)d_in[ix[6]];
    const float* b_out  = (const float*)d_in[ix[7]];
    float* out = (float*)d_out;

    // ws layout (bytes), total ~44MB
    char* base = (char*)d_ws;
    int*      deg      = (int*)(base + 0);           // 200000
    int*      bsync    = (int*)(base + 200000);      // 256 (zeroed with deg)
    int*      row_ptr  = (int*)(base + 200256);      // 200004
    int*      rank     = (int*)(base + 400272);      // 2400000
    float*    inv_deg  = (float*)(base + 2800272);   // 200000
    int*      edge_src = (int*)(base + 3000272);     // 2400000
    _Float16* WinT     = (_Float16*)(base + 5400272);
    _Float16* WcombT   = (_Float16*)(base + 5433040);
    _Float16* WoutT    = (_Float16*)(base + 5564112);
    _Float16* hA       = (_Float16*)(base + 5576448);
    _Float16* hB       = (_Float16*)(base + 18376448);
    _Float16* msg      = (_Float16*)(base + 31176448);

    hipMemsetAsync(deg, 0, 200256, stream);  // deg + bsync
    k_count_prep<<<CNT_B + WPREP_B, 256, 0, stream>>>(adj_w, deg, rank, W_in, W_comb, W_out,
                                                      WinT, WcombT, WoutT);
    k_scan<<<NBLK, 1024, 0, stream>>>(deg, row_ptr, inv_deg, bsync);
    k_fill_in<<<CNT_B + IN_B, 256, 0, stream>>>(adj_w, row_ptr, rank, edge_src,
                                                X, WinT, b_in, hA);

    k_gather<<<2048, 256, 0, stream>>>((const uint4*)hA, (uint4*)msg, row_ptr, edge_src, inv_deg);
    k_layer<<<782, 256, 0, stream>>>(hA, msg, WcombT, b_comb, hB);

    k_gather<<<2048, 256, 0, stream>>>((const uint4*)hB, (uint4*)msg, row_ptr, edge_src, inv_deg);
    k_layer_out<<<782, 256, 0, stream>>>(hB, msg, WcombT + 32768, b_comb + 128,
                                         WoutT, b_out, out);
}